// Round 16
// baseline (9386.764 us; speedup 1.0000x reference)
//
#include <hip/hip_runtime.h>
#include <hip/hip_cooperative_groups.h>
#include <hip/hip_fp16.h>
#include <math.h>

namespace cg = cooperative_groups;

#define H      4096
#define SEQ    2048
#define HOR    64
#define NBLK   256
#define NTHR   1024
#define NWAVE  (NTHR / 64)   // 16 waves, 4 per SIMD
#define J      16            // uint2 chunks per lane per row: H/(64*4)

#define NREP       8                     // replicas of the tagged h buffer
#define LINE_F     32                    // floats per 128B line (16 {h,tag} granules)
#define REP_F      (NBLK * LINE_F)       // floats per replica = 8192
#define BUF_F      (NREP * REP_F)        // floats per buffer   = 65536 (256 KB)

// LDS layout (byte offsets)
#define OFF_HHA    0                     // h packed fp16, buffer A: 8192
#define OFF_HHB    8192                  // h packed fp16, buffer B: 8192
#define OFF_HOWN   16384                 // own 16 rows fp32: 64
#define OFF_RED    16448                 // 16 AR partials: 64
#define OFF_PUB    16512                 // 16 h-publish slots: 64
#define OFF_CNT    16576                 // wave-arrival counter: 4
#define SMEM_BYTES 16580

typedef float f32x4_t __attribute__((ext_vector_type(4)));
typedef _Float16 h2_t __attribute__((ext_vector_type(2)));

__device__ __forceinline__ h2_t as_h2(unsigned u) {
    union { unsigned u; h2_t h; } c; c.u = u; return c.h;
}

// ---- fence-free L3-coherent point ops (sc0 sc1 = bypass L1+L2, served by
// memory-side Infinity Cache which is coherent across XCDs). ----
__device__ __forceinline__ void store_l3_f4(float* p, float a, float b, float c, float d) {
    f32x4_t w;
    w.x = a; w.y = b; w.z = c; w.w = d;
    asm volatile("global_store_dwordx4 %0, %1, off sc0 sc1"
                 :: "v"(p), "v"(w) : "memory");
}
__device__ __forceinline__ float4 load_l3_f4(const float4* p) {
    float4 v;
    asm volatile("global_load_dwordx4 %0, %1, off sc0 sc1"
                 : "=v"(v) : "v"(p) : "memory");
    return v;
}
__device__ __forceinline__ void vm_drain() {
    asm volatile("s_waitcnt vmcnt(0)" ::: "memory");
}

__device__ __forceinline__ float wave_reduce(float v) {
#pragma unroll
    for (int o = 32; o > 0; o >>= 1) v += __shfl_xor(v, o, 64);
    return v;
}

__device__ __forceinline__ float dot4(float4 a, float4 b) {
    float s = a.x * b.x;
    s = fmaf(a.y, b.y, s);
    s = fmaf(a.z, b.z, s);
    s = fmaf(a.w, b.w, s);
    return s;
}

union H4U { uint2 u; __half h[4]; };

__device__ __forceinline__ uint2 pack4(float4 v) {
    H4U c;
    c.h[0] = __float2half_rn(v.x); c.h[1] = __float2half_rn(v.y);
    c.h[2] = __float2half_rn(v.z); c.h[3] = __float2half_rn(v.w);
    return c.u;
}

// Fully weight-resident persistent GRU.
// R16 = R14's skeleton at 1024 threads: 16 waves (4/SIMD), 1 row per wave.
// Theory: R15 proved per-wave ILP is exhausted; the dot region's ~1.3us
// (vs ~0.2us issue floor) is latency at 2 waves/SIMD. 4 waves/SIMD halves
// per-wave work (3 accumulators, 96 fdot2) AND doubles latency hiding.
// Register budget is the gamble: 48 uint2 weights + overhead ~126/lane,
// right at the 128 ceiling for 4 waves/SIMD. launch_bounds(1024,1) forces
// fit-or-spill; FETCH_SIZE is the spill canary (clean ~381MB, spill >1GB).
// Everything else byte-identical R14: tagged replica-line exchange, backoff
// cap 8, sync1 + sync2, last-arriving-wave publish into a quiet CU port.
// Tags: float t (exact to 2112); ws poison 0xAAAAAAAA = -3e-13 < 0 fails
// every tag check; double-buffer + monotone tags + all-to-all slice
// coupling rule out WAR races.
__global__ __launch_bounds__(NTHR, 1) void gru_kernel(
    const float* __restrict__ xseq,
    const float* __restrict__ uWx, const float* __restrict__ uWh, const float* __restrict__ ubv,
    const float* __restrict__ rWx, const float* __restrict__ rWh, const float* __restrict__ rbv,
    const float* __restrict__ wxv, const float* __restrict__ Whm, const float* __restrict__ bbv,
    const float* __restrict__ Vv,  const float* __restrict__ cv,
    float* __restrict__ out, float* __restrict__ ws)
{
    cg::grid_group grid = cg::this_grid();
    extern __shared__ unsigned char smem[];
    uint2* hHa  = (uint2*)(smem + OFF_HHA);    // h fp16, buffer A (even t)
    uint2* hHb  = (uint2*)(smem + OFF_HHB);    // h fp16, buffer B (odd t)
    float* hOwn = (float*)(smem + OFF_HOWN);   // this block's 16 h values fp32
    float* red  = (float*)(smem + OFF_RED);    // 16 AR partials
    float* pub  = (float*)(smem + OFF_PUB);    // 16 h-publish slots
    int*   cnt  = (int*)(smem + OFF_CNT);      // wave-arrival counter

    const int tid  = threadIdx.x;
    const int wv   = tid >> 6;
    const int lane = tid & 63;
    const int bid  = blockIdx.x;
    const int r0   = bid * NWAVE + wv;         // this wave's single row

    float* hA = ws;            // tagged replicated buffer A (65536 floats)
    float* hB = ws + BUF_F;    // tagged replicated buffer B

    if (tid == 0) *cnt = 0;

    // ---- one-time load: pin this wave's 3 weight rows in registers ----
    const float4* w0p = (const float4*)(Whm + (size_t)r0 * H);
    const float4* u0p = (const float4*)(uWh + (size_t)r0 * H);
    const float4* p0p = (const float4*)(rWh + (size_t)r0 * H);

    uint2 wp[J], uu[J], rw[J];     // packed fp16, 96 VGPRs total

#pragma unroll
    for (int j = 0; j < J; ++j) {
        const int idx = j * 64 + lane;
        wp[j] = pack4(w0p[idx]);
        uu[j] = pack4(u0p[idx]);
        rw[j] = pack4(p0p[idx]);
    }
#pragma unroll
    for (int j = 0; j < J; ++j) {
        asm volatile("" : "+v"(wp[j].x), "+v"(wp[j].y));
        asm volatile("" : "+v"(uu[j].x), "+v"(uu[j].y));
        asm volatile("" : "+v"(rw[j].x), "+v"(rw[j].y));
    }

    const float uwx0 = uWx[r0], ub0 = ubv[r0];
    const float rwx0 = rWx[r0], rb0 = rbv[r0];
    const float wx0  = wxv[r0], bb0 = bbv[r0];
    const float c0 = cv[0];

    // ---- publish/gather address precompute ----
    // publish (by the last-arriving wave): lane l -> replica l>>3, chunk l&7
    const int psub = lane & 7;
    const int pub_off = (lane >> 3) * REP_F + bid * LINE_F + psub * 4;   // floats
    // gather: 4 lanes per source slot; thread covers 2 float4 (4 granules)
    const int gslot = wv * 16 + (lane >> 2);   // 0..255
    const int gq    = lane & 3;
    const int gat_off = (bid & (NREP - 1)) * REP_F + gslot * LINE_F + gq * 8; // floats
    const int hidx2 = gslot * 4 + gq;          // uint2 index into hH (4 h vals)
    const bool own = (gslot == bid);           // this thread holds own rows 4gq..4gq+3

    // h0 = 0, tag = 0: seed all replicas of hA (one store instruction/block)
    if (wv == 0)
        store_l3_f4(hA + pub_off, 0.f, 0.f, 0.f, 0.f);

    grid.sync();   // one-time; includes intra-block barrier + vmcnt(0) drain

    const float4* v4g = (const float4*)Vv;

#pragma unroll 1
    for (int t = 0; t < SEQ + HOR; ++t) {
        const float* hin  = (t & 1) ? hB : hA;
        float*       hout = (t & 1) ? hA : hB;
        const float tagf  = (float)t;
        const float tagf1 = (float)(t + 1);

        // ---- poll-gather own 2 float4 with exponential backoff (cap 8) ----
        const float4* src = (const float4*)(hin + gat_off);
        float4 q0, q1;
        int bk = 0;
        for (;;) {
            q0 = load_l3_f4(src);
            q1 = load_l3_f4(src + 1);
            vm_drain();
            const float mn = fminf(fminf(q0.y, q0.w), fminf(q1.y, q1.w));
            if (mn >= tagf) break;
            if      (bk == 0) { bk = 1; }
            else if (bk == 1) { __builtin_amdgcn_s_sleep(1); bk = 2; }
            else if (bk == 2) { __builtin_amdgcn_s_sleep(2); bk = 3; }
            else if (bk == 3) { __builtin_amdgcn_s_sleep(4); bk = 4; }
            else              { __builtin_amdgcn_s_sleep(8); }
        }
        // stage: 4 h values packed fp16 -> hH; own rows fp32 -> hOwn
        const float4 sa = make_float4(q0.x, q0.z, q1.x, q1.z);
        ((uint2*)((t & 1) ? hHb : hHa))[hidx2] = pack4(sa);
        if (own) {
            float* hop = hOwn + gq * 4;
            hop[0] = sa.x; hop[1] = sa.y; hop[2] = sa.z; hop[3] = sa.w;
        }
        __syncthreads();   // sync1: hH/hOwn ready

        float x;
        if (t < SEQ) {
            x = xseq[t];
        } else {
            // y = v.h + c0 from gather registers; slot/lane mapping is
            // identical in every block -> x bitwise-uniform grid-wide
            float p = dot4(sa, v4g[hidx2]);
            p = wave_reduce(p);
            if (lane == 0) red[wv] = p;
            __syncthreads();
            float y = c0;
#pragma unroll
            for (int w = 0; w < NWAVE; ++w) y += red[w];
            x = y;
            if (t > SEQ && bid == 0 && tid == 0) out[t - SEQ - 1] = y;
        }

        // ---- three row-dots via v_dot2_f32_f16 (this wave's single row) ----
        const uint2* hcur = (t & 1) ? hHb : hHa;
        float au = 0.f, ar = 0.f, aw = 0.f;
#pragma unroll
        for (int j = 0; j < J; ++j) {
            const int idx = j * 64 + lane;
            const uint2 hh = hcur[idx];          // 4 halves of this h chunk
            aw = __builtin_amdgcn_fdot2(as_h2(wp[j].x), as_h2(hh.x), aw, false);
            aw = __builtin_amdgcn_fdot2(as_h2(wp[j].y), as_h2(hh.y), aw, false);
            au = __builtin_amdgcn_fdot2(as_h2(uu[j].x), as_h2(hh.x), au, false);
            au = __builtin_amdgcn_fdot2(as_h2(uu[j].y), as_h2(hh.y), au, false);
            ar = __builtin_amdgcn_fdot2(as_h2(rw[j].x), as_h2(hh.x), ar, false);
            ar = __builtin_amdgcn_fdot2(as_h2(rw[j].y), as_h2(hh.y), ar, false);
        }
        au = wave_reduce(au);
        ar = wave_reduce(ar);
        aw = wave_reduce(aw);

        // ---- epilogue on lane 0 -> LDS pub slot ----
        if (lane == 0) {
            const float ho  = hOwn[wv];
            const float zu  = fmaf(uwx0, x, au + ub0);
            const float zr  = fmaf(rwx0, x, ar + rb0);
            const float u   = 1.f / (1.f + expf(-zu));
            const float g   = 1.f / (1.f + expf(-zr));
            const float hh  = tanhf(fmaf(wx0, x, fmaf(g, aw, bb0)));
            pub[wv] = fmaf(u, hh - ho, ho);
        }
        // ensure this wave's pub write is in LDS before its arrival bump
        asm volatile("s_waitcnt lgkmcnt(0)" ::: "memory");
        int old = 0;
        if (lane == 0) old = atomicAdd(cnt, 1);
        old = __shfl(old, 0, 64);
        if (old == NWAVE * t + (NWAVE - 1)) {
            // last-arriving wave: publish the block's 8 tagged replica lines
            // into a QUIET CU memory port (other waves park at sync2 below)
            const float h0v = pub[psub * 2], h1v = pub[psub * 2 + 1];
            store_l3_f4(hout + pub_off, h0v, tagf1, h1v, tagf1);
        }
        __syncthreads();   // sync2: keeps poll loads off the publish's port
    }

    // preds[63] from final h (t=2111 odd wrote hA with tag 2112); block 0 only
    if (bid == 0) {
        const float tagF = (float)(SEQ + HOR);
        const float4* src = (const float4*)(hA + gat_off);
        float4 q0, q1;
        int bk = 0;
        for (;;) {
            q0 = load_l3_f4(src);
            q1 = load_l3_f4(src + 1);
            vm_drain();
            const float mn = fminf(fminf(q0.y, q0.w), fminf(q1.y, q1.w));
            if (mn >= tagF) break;
            if      (bk == 0) { bk = 1; }
            else              { __builtin_amdgcn_s_sleep(2); }
        }
        const float4 sa = make_float4(q0.x, q0.z, q1.x, q1.z);
        float p = dot4(sa, v4g[hidx2]);
        p = wave_reduce(p);
        if (lane == 0) red[wv] = p;
        __syncthreads();
        if (tid == 0) {
            float y = c0;
            for (int w = 0; w < NWAVE; ++w) y += red[w];
            out[HOR - 1] = y;
        }
    }
}

extern "C" void kernel_launch(void* const* d_in, const int* in_sizes, int n_in,
                              void* d_out, int out_size, void* d_ws, size_t ws_size,
                              hipStream_t stream) {
    const float* xseq = (const float*)d_in[0];
    const float* uWx  = (const float*)d_in[2];
    const float* uWh  = (const float*)d_in[3];
    const float* ubv  = (const float*)d_in[4];
    const float* rWx  = (const float*)d_in[5];
    const float* rWh  = (const float*)d_in[6];
    const float* rbv  = (const float*)d_in[7];
    const float* wxv  = (const float*)d_in[8];
    const float* Whm  = (const float*)d_in[9];
    const float* bbv  = (const float*)d_in[10];
    const float* Vv   = (const float*)d_in[11];
    const float* cv   = (const float*)d_in[12];
    float* out = (float*)d_out;
    float* ws  = (float*)d_ws;

    (void)hipFuncSetAttribute((const void*)gru_kernel,
                              hipFuncAttributeMaxDynamicSharedMemorySize, SMEM_BYTES);

    void* args[] = { &xseq, &uWx, &uWh, &ubv, &rWx, &rWh, &rbv,
                     &wxv, &Whm, &bbv, &Vv, &cv, &out, &ws };
    (void)hipLaunchCooperativeKernel((void*)gru_kernel, dim3(NBLK), dim3(NTHR),
                                     args, SMEM_BYTES, stream);
}

// Round 17
// 8364.939 us; speedup vs baseline: 1.1222x; 1.1222x over previous
//
#include <hip/hip_runtime.h>
#include <hip/hip_cooperative_groups.h>
#include <hip/hip_fp16.h>
#include <math.h>

namespace cg = cooperative_groups;

#define H      4096
#define SEQ    2048
#define HOR    64
#define NBLK   256
#define NTHR   512
#define NWAVE  (NTHR / 64)
#define RPW    2            // rows per wave; 8 waves * 2 = 16 rows per block
#define J      16           // float4 chunks per lane per row: H/(64*4)

#define NREP       8                     // replicas of the tagged h buffer
#define LINE_F     32                    // floats per 128B line (16 {h,tag} granules)
#define REP_F      (NBLK * LINE_F)       // floats per replica = 8192
#define BUF_F      (NREP * REP_F)        // floats per buffer   = 65536 (256 KB)

// LDS layout (byte offsets) -- r_Wh lives in VGPRs; LDS is tiny
#define OFF_HHA    0                     // h packed fp16, buffer A: 8192
#define OFF_HHB    8192                  // h packed fp16, buffer B: 8192
#define OFF_HOWN   16384                 // own 16 rows fp32: 64
#define OFF_RED    16448                 // 8 AR partials: 32
#define OFF_PUB    16480                 // 16 h-publish slots: 64
#define OFF_CNT    16544                 // wave-arrival counter: 4
#define SMEM_BYTES 16576

typedef float f32x4_t __attribute__((ext_vector_type(4)));
typedef _Float16 h2_t __attribute__((ext_vector_type(2)));

__device__ __forceinline__ h2_t as_h2(unsigned u) {
    union { unsigned u; h2_t h; } c; c.u = u; return c.h;
}

// ---- fence-free L3-coherent point ops (sc0 sc1 = bypass L1+L2, served by
// memory-side Infinity Cache which is coherent across XCDs). ----
__device__ __forceinline__ void store_l3_f4(float* p, float a, float b, float c, float d) {
    f32x4_t w;
    w.x = a; w.y = b; w.z = c; w.w = d;
    asm volatile("global_store_dwordx4 %0, %1, off sc0 sc1"
                 :: "v"(p), "v"(w) : "memory");
}
__device__ __forceinline__ float4 load_l3_f4(const float4* p) {
    float4 v;
    asm volatile("global_load_dwordx4 %0, %1, off sc0 sc1"
                 : "=v"(v) : "v"(p) : "memory");
    return v;
}
__device__ __forceinline__ void vm_drain() {
    asm volatile("s_waitcnt vmcnt(0)" ::: "memory");
}

__device__ __forceinline__ float wave_reduce(float v) {
#pragma unroll
    for (int o = 32; o > 0; o >>= 1) v += __shfl_xor(v, o, 64);
    return v;
}

__device__ __forceinline__ float dot4(float4 a, float4 b) {
    float s = a.x * b.x;
    s = fmaf(a.y, b.y, s);
    s = fmaf(a.z, b.z, s);
    s = fmaf(a.w, b.w, s);
    return s;
}

union H4U { uint2 u; __half h[4]; };

__device__ __forceinline__ uint2 pack4(float4 v) {
    H4U c;
    c.h[0] = __float2half_rn(v.x); c.h[1] = __float2half_rn(v.y);
    c.h[2] = __float2half_rn(v.z); c.h[3] = __float2half_rn(v.w);
    return c.u;
}

// Fully weight-resident persistent GRU -- R17 = exact R14 revert (best
// verified: 8377us). R15 (ILP split) and R16 (1024-thread TLP) were both
// nulls per pre-committed criteria; every axis is now measured:
//   detection topology -> tagged replica lines (R6); poll rate -> backoff
//   cap 8 (R7); publish -> last-arriving wave into a quiet port + sync2
//   (R13); compute -> all-fdot2, all-register weights (R11/R14); ILP ->
//   depth-32 sufficient (R15 null); TLP -> 2 waves/SIMD optimal (R16 null).
// Remaining step budget ~3.97us = ~1.3us latency-bound dot region (ILP-null
// + TLP-null bracket it as the dependency-latency floor at this occupancy)
// + ~2.6us grid exchange (~2 sc0sc1 L3 RTTs + barriers = the coordination
// floor for 2112 serial grid-wide steps).
// Tags: float t (exact to 2112); ws poison 0xAAAAAAAA = -3e-13 < 0 fails
// every tag check; double-buffer + monotone tags + all-to-all slice
// coupling rule out WAR races.
__global__ __launch_bounds__(NTHR, 1) void gru_kernel(
    const float* __restrict__ xseq,
    const float* __restrict__ uWx, const float* __restrict__ uWh, const float* __restrict__ ubv,
    const float* __restrict__ rWx, const float* __restrict__ rWh, const float* __restrict__ rbv,
    const float* __restrict__ wxv, const float* __restrict__ Whm, const float* __restrict__ bbv,
    const float* __restrict__ Vv,  const float* __restrict__ cv,
    float* __restrict__ out, float* __restrict__ ws)
{
    cg::grid_group grid = cg::this_grid();
    extern __shared__ unsigned char smem[];
    uint2* hHa  = (uint2*)(smem + OFF_HHA);    // h fp16, buffer A (even t)
    uint2* hHb  = (uint2*)(smem + OFF_HHB);    // h fp16, buffer B (odd t)
    float* hOwn = (float*)(smem + OFF_HOWN);   // this block's 16 h values fp32
    float* red  = (float*)(smem + OFF_RED);    // 8 AR partials
    float* pub  = (float*)(smem + OFF_PUB);    // 16 h-publish slots
    int*   cnt  = (int*)(smem + OFF_CNT);      // wave-arrival counter

    const int tid  = threadIdx.x;
    const int wv   = tid >> 6;
    const int lane = tid & 63;
    const int bid  = blockIdx.x;
    const int r0   = bid * (NWAVE * RPW) + wv * RPW;
    const int r1   = r0 + 1;

    float* hA = ws;            // tagged replicated buffer A (65536 floats)
    float* hB = ws + BUF_F;    // tagged replicated buffer B

    if (tid == 0) *cnt = 0;

    // ---- one-time load: pin ALL weights in VGPRs (packed fp16) ----
    const float4* w0p = (const float4*)(Whm + (size_t)r0 * H);
    const float4* w1p = (const float4*)(Whm + (size_t)r1 * H);
    const float4* u0p = (const float4*)(uWh + (size_t)r0 * H);
    const float4* u1p = (const float4*)(uWh + (size_t)r1 * H);
    const float4* p0p = (const float4*)(rWh + (size_t)r0 * H);
    const float4* p1p = (const float4*)(rWh + (size_t)r1 * H);

    uint2  wpA[J], wpB[J];     // Wh rows, packed fp16
    uint2  uA[J], uB[J];       // u_Wh rows, packed fp16
    uint2  rA[J], rB[J];       // r_Wh rows, packed fp16

#pragma unroll
    for (int j = 0; j < J; ++j) {
        const int idx = j * 64 + lane;
        wpA[j] = pack4(w0p[idx]);
        wpB[j] = pack4(w1p[idx]);
        uA[j]  = pack4(u0p[idx]);
        uB[j]  = pack4(u1p[idx]);
        rA[j]  = pack4(p0p[idx]);
        rB[j]  = pack4(p1p[idx]);
    }
#pragma unroll
    for (int j = 0; j < J; ++j) {
        asm volatile("" : "+v"(wpA[j].x), "+v"(wpA[j].y));
        asm volatile("" : "+v"(wpB[j].x), "+v"(wpB[j].y));
        asm volatile("" : "+v"(uA[j].x), "+v"(uA[j].y));
        asm volatile("" : "+v"(uB[j].x), "+v"(uB[j].y));
        asm volatile("" : "+v"(rA[j].x), "+v"(rA[j].y));
        asm volatile("" : "+v"(rB[j].x), "+v"(rB[j].y));
    }

    const float uwx0 = uWx[r0], uwx1 = uWx[r1], ub0 = ubv[r0], ub1 = ubv[r1];
    const float rwx0 = rWx[r0], rwx1 = rWx[r1], rb0 = rbv[r0], rb1 = rbv[r1];
    const float wx0  = wxv[r0], wx1  = wxv[r1], bb0 = bbv[r0], bb1 = bbv[r1];
    const float c0 = cv[0];

    // ---- publish/gather address precompute ----
    const int prep = lane >> 3, psub = lane & 7;
    const int pub_off = prep * REP_F + bid * LINE_F + psub * 4;   // floats
    const int gslot = wv * 32 + (lane >> 1);
    const int ghalf = lane & 1;
    const int gat_off = (bid & (NREP - 1)) * REP_F + gslot * LINE_F + ghalf * 16; // floats
    const int gidx = gslot * 4 + ghalf * 2;   // float4-granularity h index (even)
    const bool own = (wv == (bid >> 5)) && ((lane >> 1) == (bid & 31));

    // h0 = 0, tag = 0: seed all replicas of hA (one store instruction/block)
    if (wv == 0)
        store_l3_f4(hA + pub_off, 0.f, 0.f, 0.f, 0.f);

    grid.sync();   // one-time; includes intra-block barrier + vmcnt(0) drain

    const float4* v4g = (const float4*)Vv;

#pragma unroll 1
    for (int t = 0; t < SEQ + HOR; ++t) {
        const float* hin  = (t & 1) ? hB : hA;
        float*       hout = (t & 1) ? hA : hB;
        const float tagf  = (float)t;
        const float tagf1 = (float)(t + 1);

        // ---- poll-gather own slice with exponential backoff (cap 8) ----
        const float4* src = (const float4*)(hin + gat_off);
        float4 q0, q1, q2, q3;
        int bk = 0;
        for (;;) {
            q0 = load_l3_f4(src);
            q1 = load_l3_f4(src + 1);
            q2 = load_l3_f4(src + 2);
            q3 = load_l3_f4(src + 3);
            vm_drain();
            const float mn = fminf(fminf(fminf(q0.y, q0.w), fminf(q1.y, q1.w)),
                                   fminf(fminf(q2.y, q2.w), fminf(q3.y, q3.w)));
            if (mn >= tagf) break;
            if      (bk == 0) { bk = 1; }
            else if (bk == 1) { __builtin_amdgcn_s_sleep(1); bk = 2; }
            else if (bk == 2) { __builtin_amdgcn_s_sleep(2); bk = 3; }
            else if (bk == 3) { __builtin_amdgcn_s_sleep(4); bk = 4; }
            else              { __builtin_amdgcn_s_sleep(8); }
        }
        // stage: packed fp16 into this step's hH buffer; own rows fp32
        const float4 sa = make_float4(q0.x, q0.z, q1.x, q1.z);
        const float4 sb = make_float4(q2.x, q2.z, q3.x, q3.z);
        const uint2 pa = pack4(sa), pb = pack4(sb);
        uint4* hHp4 = (uint4*)((t & 1) ? hHb : hHa);
        hHp4[gidx >> 1] = make_uint4(pa.x, pa.y, pb.x, pb.y);
        if (own) {
            float* hop = hOwn + ghalf * 8;
            hop[0] = sa.x; hop[1] = sa.y; hop[2] = sa.z; hop[3] = sa.w;
            hop[4] = sb.x; hop[5] = sb.y; hop[6] = sb.z; hop[7] = sb.w;
        }
        __syncthreads();   // sync1: hH/hOwn ready

        float x;
        if (t < SEQ) {
            x = xseq[t];
        } else {
            // y = v.h + c0 from gather registers; slice partition is
            // identical in every block -> x bitwise-uniform grid-wide
            float p = dot4(sa, v4g[gidx]) + dot4(sb, v4g[gidx + 1]);
            p = wave_reduce(p);
            if (lane == 0) red[wv] = p;
            __syncthreads();
            float y = c0;
#pragma unroll
            for (int w = 0; w < NWAVE; ++w) y += red[w];
            x = y;
            if (t > SEQ && bid == 0 && tid == 0) out[t - SEQ - 1] = y;
        }

        // ---- six resident row-dots, all via v_dot2_f32_f16, all-register
        //      weights; only hH b64 reads touch LDS ----
        const uint2* hcur = (t & 1) ? hHb : hHa;
        float au0 = 0.f, au1 = 0.f, ar0 = 0.f, ar1 = 0.f, aw0 = 0.f, aw1 = 0.f;
#pragma unroll
        for (int j = 0; j < J; ++j) {
            const int idx = j * 64 + lane;
            const uint2  hh = hcur[idx];         // 4 halves of this h chunk
            aw0 = __builtin_amdgcn_fdot2(as_h2(wpA[j].x), as_h2(hh.x), aw0, false);
            aw0 = __builtin_amdgcn_fdot2(as_h2(wpA[j].y), as_h2(hh.y), aw0, false);
            aw1 = __builtin_amdgcn_fdot2(as_h2(wpB[j].x), as_h2(hh.x), aw1, false);
            aw1 = __builtin_amdgcn_fdot2(as_h2(wpB[j].y), as_h2(hh.y), aw1, false);
            au0 = __builtin_amdgcn_fdot2(as_h2(uA[j].x), as_h2(hh.x), au0, false);
            au0 = __builtin_amdgcn_fdot2(as_h2(uA[j].y), as_h2(hh.y), au0, false);
            au1 = __builtin_amdgcn_fdot2(as_h2(uB[j].x), as_h2(hh.x), au1, false);
            au1 = __builtin_amdgcn_fdot2(as_h2(uB[j].y), as_h2(hh.y), au1, false);
            ar0 = __builtin_amdgcn_fdot2(as_h2(rA[j].x), as_h2(hh.x), ar0, false);
            ar0 = __builtin_amdgcn_fdot2(as_h2(rA[j].y), as_h2(hh.y), ar0, false);
            ar1 = __builtin_amdgcn_fdot2(as_h2(rB[j].x), as_h2(hh.x), ar1, false);
            ar1 = __builtin_amdgcn_fdot2(as_h2(rB[j].y), as_h2(hh.y), ar1, false);
        }
        au0 = wave_reduce(au0); au1 = wave_reduce(au1);
        ar0 = wave_reduce(ar0); ar1 = wave_reduce(ar1);
        aw0 = wave_reduce(aw0); aw1 = wave_reduce(aw1);

        // ---- epilogue on lanes 0/1 -> LDS pub slots ----
        if (lane < 2) {
            const bool s = (lane == 1);
            const float adu = s ? au1 : au0;
            const float adr = s ? ar1 : ar0;
            const float adw = s ? aw1 : aw0;
            const float uwx = s ? uwx1 : uwx0, ubb = s ? ub1 : ub0;
            const float rwx = s ? rwx1 : rwx0, rbb = s ? rb1 : rb0;
            const float wxx = s ? wx1  : wx0,  bbb = s ? bb1 : bb0;
            const float ho  = hOwn[wv * RPW + (s ? 1 : 0)];
            const float zu  = fmaf(uwx, x, adu + ubb);
            const float zr  = fmaf(rwx, x, adr + rbb);
            const float u   = 1.f / (1.f + expf(-zu));
            const float g   = 1.f / (1.f + expf(-zr));
            const float hh  = tanhf(fmaf(wxx, x, fmaf(g, adw, bbb)));
            pub[wv * RPW + (s ? 1 : 0)] = fmaf(u, hh - ho, ho);
        }
        // ensure this wave's pub writes are in LDS before its arrival bump
        asm volatile("s_waitcnt lgkmcnt(0)" ::: "memory");
        int old = 0;
        if (lane == 0) old = atomicAdd(cnt, 1);
        old = __shfl(old, 0, 64);
        if (old == 8 * t + 7) {
            // last-arriving wave: publish the block's 8 tagged replica lines
            // into a QUIET CU memory port (other waves park at sync2 below)
            const float h0v = pub[psub * 2], h1v = pub[psub * 2 + 1];
            store_l3_f4(hout + pub_off, h0v, tagf1, h1v, tagf1);
        }
        __syncthreads();   // sync2: keeps poll loads off the publish's port
    }

    // preds[63] from final h (t=2111 odd wrote hA with tag 2112); block 0 only
    if (bid == 0) {
        const float tagF = (float)(SEQ + HOR);
        const float4* src = (const float4*)(hA + gat_off);
        float4 q0, q1, q2, q3;
        int bk = 0;
        for (;;) {
            q0 = load_l3_f4(src);
            q1 = load_l3_f4(src + 1);
            q2 = load_l3_f4(src + 2);
            q3 = load_l3_f4(src + 3);
            vm_drain();
            const float mn = fminf(fminf(fminf(q0.y, q0.w), fminf(q1.y, q1.w)),
                                   fminf(fminf(q2.y, q2.w), fminf(q3.y, q3.w)));
            if (mn >= tagF) break;
            if      (bk == 0) { bk = 1; }
            else              { __builtin_amdgcn_s_sleep(2); }
        }
        const float4 sa = make_float4(q0.x, q0.z, q1.x, q1.z);
        const float4 sb = make_float4(q2.x, q2.z, q3.x, q3.z);
        float p = dot4(sa, v4g[gidx]) + dot4(sb, v4g[gidx + 1]);
        p = wave_reduce(p);
        if (lane == 0) red[wv] = p;
        __syncthreads();
        if (tid == 0) {
            float y = c0;
            for (int w = 0; w < NWAVE; ++w) y += red[w];
            out[HOR - 1] = y;
        }
    }
}

extern "C" void kernel_launch(void* const* d_in, const int* in_sizes, int n_in,
                              void* d_out, int out_size, void* d_ws, size_t ws_size,
                              hipStream_t stream) {
    const float* xseq = (const float*)d_in[0];
    const float* uWx  = (const float*)d_in[2];
    const float* uWh  = (const float*)d_in[3];
    const float* ubv  = (const float*)d_in[4];
    const float* rWx  = (const float*)d_in[5];
    const float* rWh  = (const float*)d_in[6];
    const float* rbv  = (const float*)d_in[7];
    const float* wxv  = (const float*)d_in[8];
    const float* Whm  = (const float*)d_in[9];
    const float* bbv  = (const float*)d_in[10];
    const float* Vv   = (const float*)d_in[11];
    const float* cv   = (const float*)d_in[12];
    float* out = (float*)d_out;
    float* ws  = (float*)d_ws;

    (void)hipFuncSetAttribute((const void*)gru_kernel,
                              hipFuncAttributeMaxDynamicSharedMemorySize, SMEM_BYTES);

    void* args[] = { &xseq, &uWx, &uWh, &ubv, &rWx, &rWh, &rbv,
                     &wxv, &Whm, &bbv, &Vv, &cv, &out, &ws };
    (void)hipLaunchCooperativeKernel((void*)gru_kernel, dim3(NBLK), dim3(NTHR),
                                     args, SMEM_BYTES, stream);
}